// Round 2
// baseline (877.216 us; speedup 1.0000x reference)
//
#include <hip/hip_runtime.h>

#define N_NODES 100000
#define N_EDGES 1600000
#define NB_N 391    // ceil(N_NODES/256)
#define BSHIFT 7
#define NBUCK 782   // ceil(N_NODES/128)

// ---------------- degree / normalization ----------------

__global__ __launch_bounds__(256) void k_degree(const int* __restrict__ src,
                                                const int* __restrict__ dst,
                                                unsigned* __restrict__ dout,
                                                unsigned* __restrict__ din) {
  int e = blockIdx.x * 256 + threadIdx.x;
  if (e < N_EDGES) {
    atomicAdd(&dout[src[e]], 1u);
    atomicAdd(&din[dst[e]], 1u);
  }
}

__global__ __launch_bounds__(256) void k_isqrt(const unsigned* __restrict__ dout,
                                               const unsigned* __restrict__ din,
                                               float* __restrict__ oi,
                                               float* __restrict__ ii,
                                               float* __restrict__ coi) {
  int i = blockIdx.x * 256 + threadIdx.x;
  if (i < N_NODES) {
    unsigned a = dout[i]; if (a < 1u) a = 1u;
    unsigned b = din[i];  if (b < 1u) b = 1u;
    float o = rsqrtf((float)a);
    float n = rsqrtf((float)b);
    oi[i] = o;
    ii[i] = n;
    coi[i] = o * n;  // relu(ii*agg)*oi == (ii*oi)*relu(agg), both > 0
  }
}

// ---------------- CSR build: 3-pass scan ----------------

__global__ __launch_bounds__(256) void k_scan1(const unsigned* __restrict__ din,
                                               unsigned* __restrict__ partials) {
  __shared__ unsigned sd[256];
  int t = threadIdx.x;
  int i = blockIdx.x * 256 + t;
  sd[t] = (i < N_NODES) ? din[i] : 0u;
  __syncthreads();
  for (int s = 128; s > 0; s >>= 1) {
    if (t < s) sd[t] += sd[t + s];
    __syncthreads();
  }
  if (t == 0) partials[blockIdx.x] = sd[0];
}

__global__ __launch_bounds__(512) void k_scan2(const unsigned* __restrict__ partials,
                                               unsigned* __restrict__ poff) {
  __shared__ unsigned sd[512];
  int t = threadIdx.x;
  unsigned v = (t < NB_N) ? partials[t] : 0u;
  sd[t] = v;
  __syncthreads();
  for (int d = 1; d < 512; d <<= 1) {
    unsigned a = (t >= d) ? sd[t - d] : 0u;
    __syncthreads();
    sd[t] += a;
    __syncthreads();
  }
  if (t < NB_N) poff[t] = sd[t] - v;  // exclusive
}

__global__ __launch_bounds__(256) void k_scan3(const unsigned* __restrict__ din,
                                               const unsigned* __restrict__ poff,
                                               int* __restrict__ row_ptr) {
  __shared__ unsigned sd[256];
  int t = threadIdx.x;
  int i = blockIdx.x * 256 + t;
  unsigned v = (i < N_NODES) ? din[i] : 0u;
  sd[t] = v;
  __syncthreads();
  for (int d = 1; d < 256; d <<= 1) {
    unsigned a = (t >= d) ? sd[t - d] : 0u;
    __syncthreads();
    sd[t] += a;
    __syncthreads();
  }
  if (i < N_NODES) row_ptr[i] = (int)(poff[blockIdx.x] + sd[t] - v);
  if (i == 0) row_ptr[N_NODES] = N_EDGES;
}

// ---------------- bucket-clustered CSR fill ----------------
// Pass A: scatter edges into dst-bucket-ordered buffer (packed: (dst&127)<<17|src).
// Per-bucket atomic cursors -> concurrent writes to a bucket hit adjacent slots
// -> full cache lines, write amplification ~1 (vs 16x for direct node scatter).

__global__ __launch_bounds__(256) void k_binit(const int* __restrict__ row_ptr,
                                               int* __restrict__ bcur) {
  int b = blockIdx.x * 256 + threadIdx.x;
  if (b < NBUCK) bcur[b] = row_ptr[b << BSHIFT];
}

__global__ __launch_bounds__(256) void k_scatter(const int* __restrict__ src,
                                                 const int* __restrict__ dst,
                                                 int* __restrict__ bcur,
                                                 int* __restrict__ ebuf) {
  int e = blockIdx.x * 256 + threadIdx.x;
  if (e < N_EDGES) {
    int d = dst[e];
    int slot = atomicAdd(&bcur[d >> BSHIFT], 1);
    ebuf[slot] = ((d & 127) << 17) | src[e];  // src < 2^17
  }
}

// Pass B: one block per bucket; 128 node cursors in LDS; writes confined to the
// bucket's ~8KB csr region -> clustered.

__global__ __launch_bounds__(256) void k_bfill(const int* __restrict__ ebuf,
                                               const int* __restrict__ row_ptr,
                                               int* __restrict__ csr_src) {
  __shared__ int lcur[128];
  const int b = blockIdx.x;
  const int node0 = b << BSHIFT;
  const int t = threadIdx.x;
  if (t < 128) {
    int n = node0 + t;
    lcur[t] = (n < N_NODES) ? row_ptr[n] : 0;
  }
  __syncthreads();
  int node_hi = node0 + 128; if (node_hi > N_NODES) node_hi = N_NODES;
  const int beg = row_ptr[node0];
  const int end = row_ptr[node_hi];
  for (int j = beg + t; j < end; j += 256) {
    int pk = ebuf[j];
    int slot = atomicAdd(&lcur[pk >> 17], 1);
    csr_src[slot] = pk & 0x1FFFF;
  }
}

// ---------------- GEMM1: h1 = (x * oi) @ W1  (100k x 128 x 128) ----------------

__global__ __launch_bounds__(256) void k_gemm1(const float* __restrict__ x,
                                               const float* __restrict__ oi,
                                               const float* __restrict__ W,
                                               float* __restrict__ h) {
  __shared__ float Ws[64 * 128];
  __shared__ float Xs[32 * 68];
  const int t = threadIdx.x;
  const int row0 = blockIdx.x * 32;
  const int c4 = t & 31;
  const int rg = t >> 5;
  float4 acc[4];
#pragma unroll
  for (int i = 0; i < 4; ++i) acc[i] = make_float4(0.f, 0.f, 0.f, 0.f);

  for (int kt = 0; kt < 128; kt += 64) {
#pragma unroll
    for (int j = 0; j < 8; ++j) {
      int q = t + 256 * j;
      int kk = q >> 5, cc = q & 31;
      *(float4*)(Ws + kk * 128 + 4 * cc) =
          *(const float4*)(W + (kt + kk) * 128 + 4 * cc);
    }
#pragma unroll
    for (int j = 0; j < 2; ++j) {
      int q = t + 256 * j;
      int r = q >> 4, kc = q & 15;
      float4 v = *(const float4*)(x + (size_t)(row0 + r) * 128 + kt + 4 * kc);
      float s = oi[row0 + r];
      v.x *= s; v.y *= s; v.z *= s; v.w *= s;
      *(float4*)(Xs + r * 68 + 4 * kc) = v;
    }
    __syncthreads();
#pragma unroll 4
    for (int kq = 0; kq < 16; ++kq) {
      float4 xv[4];
#pragma unroll
      for (int i = 0; i < 4; ++i)
        xv[i] = *(const float4*)(Xs + (rg * 4 + i) * 68 + 4 * kq);
#pragma unroll
      for (int kk = 0; kk < 4; ++kk) {
        float4 wv = *(const float4*)(Ws + (kq * 4 + kk) * 128 + 4 * c4);
#pragma unroll
        for (int i = 0; i < 4; ++i) {
          float xc = ((const float*)&xv[i])[kk];
          acc[i].x = fmaf(xc, wv.x, acc[i].x);
          acc[i].y = fmaf(xc, wv.y, acc[i].y);
          acc[i].z = fmaf(xc, wv.z, acc[i].z);
          acc[i].w = fmaf(xc, wv.w, acc[i].w);
        }
      }
    }
    __syncthreads();
  }
#pragma unroll
  for (int i = 0; i < 4; ++i)
    *(float4*)(h + (size_t)(row0 + rg * 4 + i) * 128 + 4 * c4) = acc[i];
}

// ---------------- AGG1: g[n] = coi[n] * relu(sum_{e: dst=n} h1[src_e]) ----------------

__global__ __launch_bounds__(256) void k_agg1(const float* __restrict__ h1,
                                              const int* __restrict__ csr_src,
                                              const int* __restrict__ row_ptr,
                                              const float* __restrict__ coi,
                                              float* __restrict__ g) {
  const int t = threadIdx.x;
  const int node = blockIdx.x * 8 + (t >> 5);
  const int c = t & 31;
  const int beg = row_ptr[node];
  const int end = row_ptr[node + 1];
  float4 acc = make_float4(0.f, 0.f, 0.f, 0.f);
  for (int j = beg; j < end; ++j) {
    int s = csr_src[j];
    float4 v = *(const float4*)(h1 + (size_t)s * 128 + 4 * c);
    acc.x += v.x; acc.y += v.y; acc.z += v.z; acc.w += v.w;
  }
  float sc = coi[node];
  acc.x = fmaxf(acc.x, 0.f) * sc;
  acc.y = fmaxf(acc.y, 0.f) * sc;
  acc.z = fmaxf(acc.z, 0.f) * sc;
  acc.w = fmaxf(acc.w, 0.f) * sc;
  *(float4*)(g + (size_t)node * 128 + 4 * c) = acc;
}

// ---------------- GEMM2: h2 = g @ W2  (100k x 128 x 40; relu/scales pre-folded) ----------------

__global__ __launch_bounds__(256) void k_gemm2(const float* __restrict__ g,
                                               const float* __restrict__ W2,
                                               float* __restrict__ h2) {
  __shared__ float Ws[128 * 40];
  __shared__ float Xs[32 * 132];
  const int t = threadIdx.x;
  const int row0 = blockIdx.x * 32;
  const int c4 = t & 15;
  const int rg = t >> 4;
#pragma unroll
  for (int j = 0; j < 5; ++j) {
    int q = t + 256 * j;
    int k = q / 10, cc = q % 10;
    *(float4*)(Ws + k * 40 + 4 * cc) = *(const float4*)(W2 + k * 40 + 4 * cc);
  }
#pragma unroll
  for (int j = 0; j < 4; ++j) {
    int q = t + 256 * j;
    int r = q >> 5, kc = q & 31;
    *(float4*)(Xs + r * 132 + 4 * kc) =
        *(const float4*)(g + (size_t)(row0 + r) * 128 + 4 * kc);
  }
  __syncthreads();
  if (c4 < 10) {
    float4 a0 = make_float4(0.f, 0.f, 0.f, 0.f);
    float4 a1 = make_float4(0.f, 0.f, 0.f, 0.f);
#pragma unroll 4
    for (int kq = 0; kq < 32; ++kq) {
      float4 x0 = *(const float4*)(Xs + (rg * 2) * 132 + 4 * kq);
      float4 x1 = *(const float4*)(Xs + (rg * 2 + 1) * 132 + 4 * kq);
#pragma unroll
      for (int kk = 0; kk < 4; ++kk) {
        float4 wv = *(const float4*)(Ws + (kq * 4 + kk) * 40 + 4 * c4);
        float xc0 = ((const float*)&x0)[kk];
        float xc1 = ((const float*)&x1)[kk];
        a0.x = fmaf(xc0, wv.x, a0.x);
        a0.y = fmaf(xc0, wv.y, a0.y);
        a0.z = fmaf(xc0, wv.z, a0.z);
        a0.w = fmaf(xc0, wv.w, a0.w);
        a1.x = fmaf(xc1, wv.x, a1.x);
        a1.y = fmaf(xc1, wv.y, a1.y);
        a1.z = fmaf(xc1, wv.z, a1.z);
        a1.w = fmaf(xc1, wv.w, a1.w);
      }
    }
    *(float4*)(h2 + (size_t)(row0 + rg * 2) * 40 + 4 * c4) = a0;
    *(float4*)(h2 + (size_t)(row0 + rg * 2 + 1) * 40 + 4 * c4) = a1;
  }
}

// ---------------- AGG2: out[n] = ii[n] * sum h2[src_e]  (40 ch) ----------------

__global__ __launch_bounds__(256) void k_agg2(const float* __restrict__ h2,
                                              const int* __restrict__ csr_src,
                                              const int* __restrict__ row_ptr,
                                              const float* __restrict__ ii,
                                              float* __restrict__ out) {
  const int t = threadIdx.x;
  const int node = blockIdx.x * 16 + (t >> 4);
  const int c = t & 15;
  if (c < 10) {
    const int beg = row_ptr[node];
    const int end = row_ptr[node + 1];
    float4 acc = make_float4(0.f, 0.f, 0.f, 0.f);
    for (int j = beg; j < end; ++j) {
      int s = csr_src[j];
      float4 v = *(const float4*)(h2 + (size_t)s * 40 + 4 * c);
      acc.x += v.x; acc.y += v.y; acc.z += v.z; acc.w += v.w;
    }
    float sc = ii[node];
    acc.x *= sc; acc.y *= sc; acc.z *= sc; acc.w *= sc;
    *(float4*)(out + (size_t)node * 40 + 4 * c) = acc;
  }
}

// ---------------- launch ----------------

extern "C" void kernel_launch(void* const* d_in, const int* in_sizes, int n_in,
                              void* d_out, int out_size, void* d_ws, size_t ws_size,
                              hipStream_t stream) {
  const float* x  = (const float*)d_in[0];
  const int* ei   = (const int*)d_in[1];
  const float* W1 = (const float*)d_in[2];
  const float* W2 = (const float*)d_in[3];
  const int* src = ei;
  const int* dst = ei + N_EDGES;
  float* out = (float*)d_out;

  char* p = (char*)d_ws;
  auto alloc = [&](size_t b) -> void* {
    char* r = p;
    p += (b + 255) & ~(size_t)255;
    return (void*)r;
  };
  unsigned* deg_out  = (unsigned*)alloc((size_t)N_NODES * 4);
  unsigned* deg_in   = (unsigned*)alloc((size_t)N_NODES * 4);
  int* row_ptr       = (int*)alloc((size_t)(N_NODES + 1) * 4);
  float* oi          = (float*)alloc((size_t)N_NODES * 4);
  float* ii          = (float*)alloc((size_t)N_NODES * 4);
  float* coi         = (float*)alloc((size_t)N_NODES * 4);
  unsigned* partials = (unsigned*)alloc((size_t)NB_N * 4);
  unsigned* poff     = (unsigned*)alloc((size_t)NB_N * 4);
  int* bcur          = (int*)alloc((size_t)NBUCK * 4);
  int* ebuf          = (int*)alloc((size_t)N_EDGES * 4);
  int* csr_src       = (int*)alloc((size_t)N_EDGES * 4);
  float* h1          = (float*)alloc((size_t)N_NODES * 128 * 4);
  float* g           = (float*)alloc((size_t)N_NODES * 128 * 4);
  float* h2          = (float*)alloc((size_t)N_NODES * 40 * 4);

  hipMemsetAsync(deg_out, 0, (size_t)N_NODES * 4, stream);
  hipMemsetAsync(deg_in, 0, (size_t)N_NODES * 4, stream);
  k_degree<<<N_EDGES / 256, 256, 0, stream>>>(src, dst, deg_out, deg_in);
  k_isqrt<<<NB_N, 256, 0, stream>>>(deg_out, deg_in, oi, ii, coi);
  k_scan1<<<NB_N, 256, 0, stream>>>(deg_in, partials);
  k_scan2<<<1, 512, 0, stream>>>(partials, poff);
  k_scan3<<<NB_N, 256, 0, stream>>>(deg_in, poff, row_ptr);
  k_binit<<<(NBUCK + 255) / 256, 256, 0, stream>>>(row_ptr, bcur);
  k_scatter<<<N_EDGES / 256, 256, 0, stream>>>(src, dst, bcur, ebuf);
  k_bfill<<<NBUCK, 256, 0, stream>>>(ebuf, row_ptr, csr_src);
  k_gemm1<<<N_NODES / 32, 256, 0, stream>>>(x, oi, W1, h1);
  k_agg1<<<N_NODES / 8, 256, 0, stream>>>(h1, csr_src, row_ptr, coi, g);
  k_gemm2<<<N_NODES / 32, 256, 0, stream>>>(g, W2, h2);
  k_agg2<<<N_NODES / 16, 256, 0, stream>>>(h2, csr_src, row_ptr, ii, out);
}

// Round 3
// 464.632 us; speedup vs baseline: 1.8880x; 1.8880x over previous
//
#include <hip/hip_runtime.h>

#define N_NODES 100000
#define N_EDGES 1600000
#define BSHIFT 7
#define NBUCK 782    // ceil(N_NODES/128)
#define NCHUNK 256
#define CH 6250      // N_EDGES / NCHUNK exactly

// ---------------- src out-degree (for oi) ----------------

__global__ __launch_bounds__(256) void k_degree_src(const int* __restrict__ src,
                                                    unsigned* __restrict__ dout) {
  int e = blockIdx.x * 256 + threadIdx.x;
  if (e < N_EDGES) atomicAdd(&dout[src[e]], 1u);
}

__global__ __launch_bounds__(256) void k_isqrt_o(const unsigned* __restrict__ dout,
                                                 float* __restrict__ oi) {
  int i = blockIdx.x * 256 + threadIdx.x;
  if (i < N_NODES) {
    unsigned a = dout[i]; if (a < 1u) a = 1u;
    oi[i] = rsqrtf((float)a);
  }
}

// ---------------- deterministic counting-sort partition (no global atomics) ----------------
// Pass 1: per-chunk LDS histogram over 782 dst-buckets.

__global__ __launch_bounds__(256) void k_hist(const int* __restrict__ dst,
                                              unsigned* __restrict__ histG) {
  __shared__ unsigned h[NBUCK];
  const int t = threadIdx.x, j = blockIdx.x;
  for (int i = t; i < NBUCK; i += 256) h[i] = 0u;
  __syncthreads();
  const int e0 = j * CH;
  for (int e = e0 + t; e < e0 + CH; e += 256)
    atomicAdd(&h[(unsigned)dst[e] >> BSHIFT], 1u);
  __syncthreads();
  for (int i = t; i < NBUCK; i += 256) histG[(size_t)i * NCHUNK + j] = h[i];
}

// Pass 2: one wave per bucket — exclusive scan of its 256 chunk-counts (in place)
// + bucket total.

__global__ __launch_bounds__(256) void k_offs(unsigned* __restrict__ histG,
                                              unsigned* __restrict__ btot) {
  const int bu = blockIdx.x * 4 + (threadIdx.x >> 6);
  if (bu >= NBUCK) return;
  const int lane = threadIdx.x & 63;
  unsigned* col = histG + (size_t)bu * NCHUNK;
  unsigned v[4], s = 0;
#pragma unroll
  for (int i = 0; i < 4; ++i) { v[i] = col[lane * 4 + i]; s += v[i]; }
  unsigned x = s;
#pragma unroll
  for (int d = 1; d < 64; d <<= 1) {
    unsigned y = __shfl_up(x, d, 64);
    if (lane >= d) x += y;
  }
  unsigned run = x - s;  // exclusive prefix across lanes
#pragma unroll
  for (int i = 0; i < 4; ++i) { unsigned tv = v[i]; col[lane * 4 + i] = run; run += tv; }
  if (lane == 63) btot[bu] = run;
}

// Pass 3: scan bucket totals -> bucket bases.

__global__ __launch_bounds__(1024) void k_bscan(const unsigned* __restrict__ btot,
                                                int* __restrict__ bbase,
                                                int* __restrict__ row_ptr) {
  __shared__ unsigned sd[1024];
  const int t = threadIdx.x;
  unsigned v = (t < NBUCK) ? btot[t] : 0u;
  sd[t] = v;
  __syncthreads();
  for (int d = 1; d < 1024; d <<= 1) {
    unsigned a = (t >= d) ? sd[t - d] : 0u;
    __syncthreads();
    sd[t] += a;
    __syncthreads();
  }
  if (t < NBUCK) bbase[t] = (int)(sd[t] - v);
  if (t == 0) { bbase[NBUCK] = N_EDGES; row_ptr[N_NODES] = N_EDGES; }
}

// Pass 4: re-read edges, deterministic slot via LDS cursors (no global atomics).
// Packed entry: (dst&127)<<17 | src   (src < 2^17).

__global__ __launch_bounds__(256) void k_part(const int* __restrict__ src,
                                              const int* __restrict__ dst,
                                              const unsigned* __restrict__ histG,
                                              const int* __restrict__ bbase,
                                              int* __restrict__ ebuf) {
  __shared__ unsigned lcur[NBUCK];
  __shared__ int lbase[NBUCK];
  const int t = threadIdx.x, j = blockIdx.x;
  for (int i = t; i < NBUCK; i += 256) {
    lcur[i] = histG[(size_t)i * NCHUNK + j];
    lbase[i] = bbase[i];
  }
  __syncthreads();
  const int e0 = j * CH;
  for (int e = e0 + t; e < e0 + CH; e += 256) {
    int d = dst[e], s = src[e];
    int bu = (unsigned)d >> BSHIFT;
    unsigned r = atomicAdd(&lcur[bu], 1u);
    ebuf[lbase[bu] + (int)r] = ((d & 127) << 17) | s;
  }
}

// Pass 5: block per bucket — per-node counts (LDS) -> row_ptr/ii/coi, then
// clustered csr_src fill.

__global__ __launch_bounds__(256) void k_bfill2(const int* __restrict__ ebuf,
                                                const int* __restrict__ bbase,
                                                const float* __restrict__ oi,
                                                int* __restrict__ row_ptr,
                                                int* __restrict__ csr_src,
                                                float* __restrict__ ii,
                                                float* __restrict__ coi) {
  __shared__ unsigned cnt[128];
  __shared__ int start[128];
  const int b = blockIdx.x, t = threadIdx.x;
  const int node0 = b << BSHIFT;
  const int base = bbase[b], end = bbase[b + 1];
  if (t < 128) cnt[t] = 0u;
  __syncthreads();
  for (int j = base + t; j < end; j += 256)
    atomicAdd(&cnt[(unsigned)ebuf[j] >> 17], 1u);
  __syncthreads();
  if (t == 0) {
    int r = 0;
    for (int i = 0; i < 128; ++i) { start[i] = r; r += (int)cnt[i]; }
  }
  __syncthreads();
  if (t < 128) {
    int n = node0 + t;
    if (n < N_NODES) {
      row_ptr[n] = base + start[t];
      unsigned c = cnt[t]; if (c < 1u) c = 1u;
      float iv = rsqrtf((float)c);
      ii[n] = iv;
      coi[n] = iv * oi[n];  // relu(ii*agg)*oi == (ii*oi)*relu(agg)
    }
  }
  __syncthreads();
  if (t < 128) cnt[t] = (unsigned)start[t];  // reuse as cursors
  __syncthreads();
  for (int j = base + t; j < end; j += 256) {
    int pk = ebuf[j];
    unsigned dn = (unsigned)pk >> 17;
    unsigned slot = atomicAdd(&cnt[dn], 1u);
    csr_src[base + (int)slot] = pk & 0x1FFFF;
  }
}

// ---------------- GEMM1: h1 = (x * oi) @ W1  (100k x 128 x 128) ----------------

__global__ __launch_bounds__(256) void k_gemm1(const float* __restrict__ x,
                                               const float* __restrict__ oi,
                                               const float* __restrict__ W,
                                               float* __restrict__ h) {
  __shared__ float Ws[64 * 128];
  __shared__ float Xs[32 * 68];
  const int t = threadIdx.x;
  const int row0 = blockIdx.x * 32;
  const int c4 = t & 31;
  const int rg = t >> 5;
  float4 acc[4];
#pragma unroll
  for (int i = 0; i < 4; ++i) acc[i] = make_float4(0.f, 0.f, 0.f, 0.f);

  for (int kt = 0; kt < 128; kt += 64) {
#pragma unroll
    for (int j = 0; j < 8; ++j) {
      int q = t + 256 * j;
      int kk = q >> 5, cc = q & 31;
      *(float4*)(Ws + kk * 128 + 4 * cc) =
          *(const float4*)(W + (kt + kk) * 128 + 4 * cc);
    }
#pragma unroll
    for (int j = 0; j < 2; ++j) {
      int q = t + 256 * j;
      int r = q >> 4, kc = q & 15;
      float4 v = *(const float4*)(x + (size_t)(row0 + r) * 128 + kt + 4 * kc);
      float s = oi[row0 + r];
      v.x *= s; v.y *= s; v.z *= s; v.w *= s;
      *(float4*)(Xs + r * 68 + 4 * kc) = v;
    }
    __syncthreads();
#pragma unroll 4
    for (int kq = 0; kq < 16; ++kq) {
      float4 xv[4];
#pragma unroll
      for (int i = 0; i < 4; ++i)
        xv[i] = *(const float4*)(Xs + (rg * 4 + i) * 68 + 4 * kq);
#pragma unroll
      for (int kk = 0; kk < 4; ++kk) {
        float4 wv = *(const float4*)(Ws + (kq * 4 + kk) * 128 + 4 * c4);
#pragma unroll
        for (int i = 0; i < 4; ++i) {
          float xc = ((const float*)&xv[i])[kk];
          acc[i].x = fmaf(xc, wv.x, acc[i].x);
          acc[i].y = fmaf(xc, wv.y, acc[i].y);
          acc[i].z = fmaf(xc, wv.z, acc[i].z);
          acc[i].w = fmaf(xc, wv.w, acc[i].w);
        }
      }
    }
    __syncthreads();
  }
#pragma unroll
  for (int i = 0; i < 4; ++i)
    *(float4*)(h + (size_t)(row0 + rg * 4 + i) * 128 + 4 * c4) = acc[i];
}

// ---------------- AGG1: g[n] = coi[n] * relu(sum_{e: dst=n} h1[src_e]) ----------------

__global__ __launch_bounds__(256) void k_agg1(const float* __restrict__ h1,
                                              const int* __restrict__ csr_src,
                                              const int* __restrict__ row_ptr,
                                              const float* __restrict__ coi,
                                              float* __restrict__ g) {
  const int t = threadIdx.x;
  const int node = blockIdx.x * 8 + (t >> 5);
  const int c = t & 31;
  const int beg = row_ptr[node];
  const int end = row_ptr[node + 1];
  float4 acc = make_float4(0.f, 0.f, 0.f, 0.f);
  for (int j = beg; j < end; ++j) {
    int s = csr_src[j];
    float4 v = *(const float4*)(h1 + (size_t)s * 128 + 4 * c);
    acc.x += v.x; acc.y += v.y; acc.z += v.z; acc.w += v.w;
  }
  float sc = coi[node];
  acc.x = fmaxf(acc.x, 0.f) * sc;
  acc.y = fmaxf(acc.y, 0.f) * sc;
  acc.z = fmaxf(acc.z, 0.f) * sc;
  acc.w = fmaxf(acc.w, 0.f) * sc;
  *(float4*)(g + (size_t)node * 128 + 4 * c) = acc;
}

// ---------------- GEMM2: h2 = g @ W2  (100k x 128 x 40) ----------------

__global__ __launch_bounds__(256) void k_gemm2(const float* __restrict__ g,
                                               const float* __restrict__ W2,
                                               float* __restrict__ h2) {
  __shared__ float Ws[128 * 40];
  __shared__ float Xs[32 * 132];
  const int t = threadIdx.x;
  const int row0 = blockIdx.x * 32;
  const int c4 = t & 15;
  const int rg = t >> 4;
#pragma unroll
  for (int j = 0; j < 5; ++j) {
    int q = t + 256 * j;
    int k = q / 10, cc = q % 10;
    *(float4*)(Ws + k * 40 + 4 * cc) = *(const float4*)(W2 + k * 40 + 4 * cc);
  }
#pragma unroll
  for (int j = 0; j < 4; ++j) {
    int q = t + 256 * j;
    int r = q >> 5, kc = q & 31;
    *(float4*)(Xs + r * 132 + 4 * kc) =
        *(const float4*)(g + (size_t)(row0 + r) * 128 + 4 * kc);
  }
  __syncthreads();
  if (c4 < 10) {
    float4 a0 = make_float4(0.f, 0.f, 0.f, 0.f);
    float4 a1 = make_float4(0.f, 0.f, 0.f, 0.f);
#pragma unroll 4
    for (int kq = 0; kq < 32; ++kq) {
      float4 x0 = *(const float4*)(Xs + (rg * 2) * 132 + 4 * kq);
      float4 x1 = *(const float4*)(Xs + (rg * 2 + 1) * 132 + 4 * kq);
#pragma unroll
      for (int kk = 0; kk < 4; ++kk) {
        float4 wv = *(const float4*)(Ws + (kq * 4 + kk) * 40 + 4 * c4);
        float xc0 = ((const float*)&x0)[kk];
        float xc1 = ((const float*)&x1)[kk];
        a0.x = fmaf(xc0, wv.x, a0.x);
        a0.y = fmaf(xc0, wv.y, a0.y);
        a0.z = fmaf(xc0, wv.z, a0.z);
        a0.w = fmaf(xc0, wv.w, a0.w);
        a1.x = fmaf(xc1, wv.x, a1.x);
        a1.y = fmaf(xc1, wv.y, a1.y);
        a1.z = fmaf(xc1, wv.z, a1.z);
        a1.w = fmaf(xc1, wv.w, a1.w);
      }
    }
    *(float4*)(h2 + (size_t)(row0 + rg * 2) * 40 + 4 * c4) = a0;
    *(float4*)(h2 + (size_t)(row0 + rg * 2 + 1) * 40 + 4 * c4) = a1;
  }
}

// ---------------- AGG2: out[n] = ii[n] * sum h2[src_e]  (40 ch) ----------------

__global__ __launch_bounds__(256) void k_agg2(const float* __restrict__ h2,
                                              const int* __restrict__ csr_src,
                                              const int* __restrict__ row_ptr,
                                              const float* __restrict__ ii,
                                              float* __restrict__ out) {
  const int t = threadIdx.x;
  const int node = blockIdx.x * 16 + (t >> 4);
  const int c = t & 15;
  if (c < 10) {
    const int beg = row_ptr[node];
    const int end = row_ptr[node + 1];
    float4 acc = make_float4(0.f, 0.f, 0.f, 0.f);
    for (int j = beg; j < end; ++j) {
      int s = csr_src[j];
      float4 v = *(const float4*)(h2 + (size_t)s * 40 + 4 * c);
      acc.x += v.x; acc.y += v.y; acc.z += v.z; acc.w += v.w;
    }
    float sc = ii[node];
    acc.x *= sc; acc.y *= sc; acc.z *= sc; acc.w *= sc;
    *(float4*)(out + (size_t)node * 40 + 4 * c) = acc;
  }
}

// ---------------- launch ----------------

extern "C" void kernel_launch(void* const* d_in, const int* in_sizes, int n_in,
                              void* d_out, int out_size, void* d_ws, size_t ws_size,
                              hipStream_t stream) {
  const float* x  = (const float*)d_in[0];
  const int* ei   = (const int*)d_in[1];
  const float* W1 = (const float*)d_in[2];
  const float* W2 = (const float*)d_in[3];
  const int* src = ei;
  const int* dst = ei + N_EDGES;
  float* out = (float*)d_out;

  char* p = (char*)d_ws;
  auto alloc = [&](size_t b) -> void* {
    char* r = p;
    p += (b + 255) & ~(size_t)255;
    return (void*)r;
  };
  unsigned* deg_out = (unsigned*)alloc((size_t)N_NODES * 4);
  float* oi         = (float*)alloc((size_t)N_NODES * 4);
  float* ii         = (float*)alloc((size_t)N_NODES * 4);
  float* coi        = (float*)alloc((size_t)N_NODES * 4);
  int* row_ptr      = (int*)alloc((size_t)(N_NODES + 1) * 4);
  unsigned* histG   = (unsigned*)alloc((size_t)NBUCK * NCHUNK * 4);
  unsigned* btot    = (unsigned*)alloc((size_t)NBUCK * 4);
  int* bbase        = (int*)alloc((size_t)(NBUCK + 1) * 4);
  int* ebuf         = (int*)alloc((size_t)N_EDGES * 4);
  int* csr_src      = (int*)alloc((size_t)N_EDGES * 4);
  float* h1         = (float*)alloc((size_t)N_NODES * 128 * 4);
  float* g          = (float*)alloc((size_t)N_NODES * 128 * 4);
  float* h2         = (float*)alloc((size_t)N_NODES * 40 * 4);

  hipMemsetAsync(deg_out, 0, (size_t)N_NODES * 4, stream);
  k_degree_src<<<N_EDGES / 256, 256, 0, stream>>>(src, deg_out);
  k_isqrt_o<<<(N_NODES + 255) / 256, 256, 0, stream>>>(deg_out, oi);
  k_hist<<<NCHUNK, 256, 0, stream>>>(dst, histG);
  k_offs<<<(NBUCK + 3) / 4, 256, 0, stream>>>(histG, btot);
  k_bscan<<<1, 1024, 0, stream>>>(btot, bbase, row_ptr);
  k_part<<<NCHUNK, 256, 0, stream>>>(src, dst, histG, bbase, ebuf);
  k_bfill2<<<NBUCK, 256, 0, stream>>>(ebuf, bbase, oi, row_ptr, csr_src, ii, coi);
  k_gemm1<<<N_NODES / 32, 256, 0, stream>>>(x, oi, W1, h1);
  k_agg1<<<N_NODES / 8, 256, 0, stream>>>(h1, csr_src, row_ptr, coi, g);
  k_gemm2<<<N_NODES / 32, 256, 0, stream>>>(g, W2, h2);
  k_agg2<<<N_NODES / 16, 256, 0, stream>>>(h2, csr_src, row_ptr, ii, out);
}

// Round 4
// 417.936 us; speedup vs baseline: 2.0989x; 1.1117x over previous
//
#include <hip/hip_runtime.h>

#define N_NODES 100000
#define N_EDGES 1600000
#define BSHIFT 7
#define NBUCK 782    // ceil(N_NODES/128)
#define NCHUNK 256
#define CH 6250      // N_EDGES / NCHUNK exactly

// bf16 helpers: pack fp32 -> bf16 (RTNE), unpack = shift into high half.
__device__ __forceinline__ unsigned pack_bf16x2(float a, float b) {
  unsigned ua = __float_as_uint(a);
  unsigned ub = __float_as_uint(b);
  ua = ua + 0x7fffu + ((ua >> 16) & 1u);
  ub = ub + 0x7fffu + ((ub >> 16) & 1u);
  return (ua >> 16) | (ub & 0xffff0000u);
}
__device__ __forceinline__ float bf_lo(unsigned u) { return __uint_as_float(u << 16); }
__device__ __forceinline__ float bf_hi(unsigned u) { return __uint_as_float(u & 0xffff0000u); }

// ---------------- src out-degree (for oi) ----------------

__global__ __launch_bounds__(256) void k_degree_src(const int* __restrict__ src,
                                                    unsigned* __restrict__ dout) {
  int e = blockIdx.x * 256 + threadIdx.x;
  if (e < N_EDGES) atomicAdd(&dout[src[e]], 1u);
}

__global__ __launch_bounds__(256) void k_isqrt_o(const unsigned* __restrict__ dout,
                                                 float* __restrict__ oi) {
  int i = blockIdx.x * 256 + threadIdx.x;
  if (i < N_NODES) {
    unsigned a = dout[i]; if (a < 1u) a = 1u;
    oi[i] = rsqrtf((float)a);
  }
}

// ---------------- deterministic counting-sort partition (no global atomics) ----------------

__global__ __launch_bounds__(256) void k_hist(const int* __restrict__ dst,
                                              unsigned* __restrict__ histG) {
  __shared__ unsigned h[NBUCK];
  const int t = threadIdx.x, j = blockIdx.x;
  for (int i = t; i < NBUCK; i += 256) h[i] = 0u;
  __syncthreads();
  const int e0 = j * CH;
  for (int e = e0 + t; e < e0 + CH; e += 256)
    atomicAdd(&h[(unsigned)dst[e] >> BSHIFT], 1u);
  __syncthreads();
  for (int i = t; i < NBUCK; i += 256) histG[(size_t)i * NCHUNK + j] = h[i];
}

__global__ __launch_bounds__(256) void k_offs(unsigned* __restrict__ histG,
                                              unsigned* __restrict__ btot) {
  const int bu = blockIdx.x * 4 + (threadIdx.x >> 6);
  if (bu >= NBUCK) return;
  const int lane = threadIdx.x & 63;
  unsigned* col = histG + (size_t)bu * NCHUNK;
  unsigned v[4], s = 0;
#pragma unroll
  for (int i = 0; i < 4; ++i) { v[i] = col[lane * 4 + i]; s += v[i]; }
  unsigned x = s;
#pragma unroll
  for (int d = 1; d < 64; d <<= 1) {
    unsigned y = __shfl_up(x, d, 64);
    if (lane >= d) x += y;
  }
  unsigned run = x - s;
#pragma unroll
  for (int i = 0; i < 4; ++i) { unsigned tv = v[i]; col[lane * 4 + i] = run; run += tv; }
  if (lane == 63) btot[bu] = run;
}

__global__ __launch_bounds__(1024) void k_bscan(const unsigned* __restrict__ btot,
                                                int* __restrict__ bbase,
                                                int* __restrict__ row_ptr) {
  __shared__ unsigned sd[1024];
  const int t = threadIdx.x;
  unsigned v = (t < NBUCK) ? btot[t] : 0u;
  sd[t] = v;
  __syncthreads();
  for (int d = 1; d < 1024; d <<= 1) {
    unsigned a = (t >= d) ? sd[t - d] : 0u;
    __syncthreads();
    sd[t] += a;
    __syncthreads();
  }
  if (t < NBUCK) bbase[t] = (int)(sd[t] - v);
  if (t == 0) { bbase[NBUCK] = N_EDGES; row_ptr[N_NODES] = N_EDGES; }
}

__global__ __launch_bounds__(256) void k_part(const int* __restrict__ src,
                                              const int* __restrict__ dst,
                                              const unsigned* __restrict__ histG,
                                              const int* __restrict__ bbase,
                                              int* __restrict__ ebuf) {
  __shared__ unsigned lcur[NBUCK];
  __shared__ int lbase[NBUCK];
  const int t = threadIdx.x, j = blockIdx.x;
  for (int i = t; i < NBUCK; i += 256) {
    lcur[i] = histG[(size_t)i * NCHUNK + j];
    lbase[i] = bbase[i];
  }
  __syncthreads();
  const int e0 = j * CH;
  for (int e = e0 + t; e < e0 + CH; e += 256) {
    int d = dst[e], s = src[e];
    int bu = (unsigned)d >> BSHIFT;
    unsigned r = atomicAdd(&lcur[bu], 1u);
    ebuf[lbase[bu] + (int)r] = ((d & 127) << 17) | s;
  }
}

__global__ __launch_bounds__(256) void k_bfill2(const int* __restrict__ ebuf,
                                                const int* __restrict__ bbase,
                                                const float* __restrict__ oi,
                                                int* __restrict__ row_ptr,
                                                int* __restrict__ csr_src,
                                                float* __restrict__ ii,
                                                float* __restrict__ coi) {
  __shared__ unsigned cnt[128];
  __shared__ int start[128];
  const int b = blockIdx.x, t = threadIdx.x;
  const int node0 = b << BSHIFT;
  const int base = bbase[b], end = bbase[b + 1];
  if (t < 128) cnt[t] = 0u;
  __syncthreads();
  for (int j = base + t; j < end; j += 256)
    atomicAdd(&cnt[(unsigned)ebuf[j] >> 17], 1u);
  __syncthreads();
  if (t == 0) {
    int r = 0;
    for (int i = 0; i < 128; ++i) { start[i] = r; r += (int)cnt[i]; }
  }
  __syncthreads();
  if (t < 128) {
    int n = node0 + t;
    if (n < N_NODES) {
      row_ptr[n] = base + start[t];
      unsigned c = cnt[t]; if (c < 1u) c = 1u;
      float iv = rsqrtf((float)c);
      ii[n] = iv;
      coi[n] = iv * oi[n];  // relu(ii*agg)*oi == (ii*oi)*relu(agg)
    }
  }
  __syncthreads();
  if (t < 128) cnt[t] = (unsigned)start[t];
  __syncthreads();
  for (int j = base + t; j < end; j += 256) {
    int pk = ebuf[j];
    unsigned dn = (unsigned)pk >> 17;
    unsigned slot = atomicAdd(&cnt[dn], 1u);
    csr_src[base + (int)slot] = pk & 0x1FFFF;
  }
}

// ---------------- GEMM1: h1(bf16) = (x * oi) @ W1  (100k x 128 x 128) ----------------

__global__ __launch_bounds__(256) void k_gemm1(const float* __restrict__ x,
                                               const float* __restrict__ oi,
                                               const float* __restrict__ W,
                                               unsigned* __restrict__ h1b) {
  __shared__ float Ws[64 * 128];
  __shared__ float Xs[32 * 68];
  const int t = threadIdx.x;
  const int row0 = blockIdx.x * 32;
  const int c4 = t & 31;
  const int rg = t >> 5;
  float4 acc[4];
#pragma unroll
  for (int i = 0; i < 4; ++i) acc[i] = make_float4(0.f, 0.f, 0.f, 0.f);

  for (int kt = 0; kt < 128; kt += 64) {
#pragma unroll
    for (int j = 0; j < 8; ++j) {
      int q = t + 256 * j;
      int kk = q >> 5, cc = q & 31;
      *(float4*)(Ws + kk * 128 + 4 * cc) =
          *(const float4*)(W + (kt + kk) * 128 + 4 * cc);
    }
#pragma unroll
    for (int j = 0; j < 2; ++j) {
      int q = t + 256 * j;
      int r = q >> 4, kc = q & 15;
      float4 v = *(const float4*)(x + (size_t)(row0 + r) * 128 + kt + 4 * kc);
      float s = oi[row0 + r];
      v.x *= s; v.y *= s; v.z *= s; v.w *= s;
      *(float4*)(Xs + r * 68 + 4 * kc) = v;
    }
    __syncthreads();
#pragma unroll 4
    for (int kq = 0; kq < 16; ++kq) {
      float4 xv[4];
#pragma unroll
      for (int i = 0; i < 4; ++i)
        xv[i] = *(const float4*)(Xs + (rg * 4 + i) * 68 + 4 * kq);
#pragma unroll
      for (int kk = 0; kk < 4; ++kk) {
        float4 wv = *(const float4*)(Ws + (kq * 4 + kk) * 128 + 4 * c4);
#pragma unroll
        for (int i = 0; i < 4; ++i) {
          float xc = ((const float*)&xv[i])[kk];
          acc[i].x = fmaf(xc, wv.x, acc[i].x);
          acc[i].y = fmaf(xc, wv.y, acc[i].y);
          acc[i].z = fmaf(xc, wv.z, acc[i].z);
          acc[i].w = fmaf(xc, wv.w, acc[i].w);
        }
      }
    }
    __syncthreads();
  }
  // pack to bf16: row stride 64 uints, this thread covers cols 4*c4..4*c4+3
#pragma unroll
  for (int i = 0; i < 4; ++i) {
    uint2 pk;
    pk.x = pack_bf16x2(acc[i].x, acc[i].y);
    pk.y = pack_bf16x2(acc[i].z, acc[i].w);
    *(uint2*)(h1b + (size_t)(row0 + rg * 4 + i) * 64 + 2 * c4) = pk;
  }
}

// ---------------- AGG1: g[n] = coi[n] * relu(sum h1[src])  (bf16 gather, fp32 acc) ----------------
// 16 lanes per node (uint4 = 8 bf16 each), 16 nodes per block.

__global__ __launch_bounds__(256) void k_agg1(const unsigned* __restrict__ h1b,
                                              const int* __restrict__ csr_src,
                                              const int* __restrict__ row_ptr,
                                              const float* __restrict__ coi,
                                              float* __restrict__ g) {
  const int t = threadIdx.x;
  const int node = blockIdx.x * 16 + (t >> 4);
  const int c = t & 15;
  const int beg = row_ptr[node];
  const int end = row_ptr[node + 1];
  float4 a0 = make_float4(0.f, 0.f, 0.f, 0.f);
  float4 a1 = make_float4(0.f, 0.f, 0.f, 0.f);
  for (int j = beg; j < end; ++j) {
    int s = csr_src[j];
    uint4 v = *(const uint4*)(h1b + (size_t)s * 64 + 4 * c);
    a0.x += bf_lo(v.x); a0.y += bf_hi(v.x);
    a0.z += bf_lo(v.y); a0.w += bf_hi(v.y);
    a1.x += bf_lo(v.z); a1.y += bf_hi(v.z);
    a1.z += bf_lo(v.w); a1.w += bf_hi(v.w);
  }
  float sc = coi[node];
  a0.x = fmaxf(a0.x, 0.f) * sc; a0.y = fmaxf(a0.y, 0.f) * sc;
  a0.z = fmaxf(a0.z, 0.f) * sc; a0.w = fmaxf(a0.w, 0.f) * sc;
  a1.x = fmaxf(a1.x, 0.f) * sc; a1.y = fmaxf(a1.y, 0.f) * sc;
  a1.z = fmaxf(a1.z, 0.f) * sc; a1.w = fmaxf(a1.w, 0.f) * sc;
  float* go = g + (size_t)node * 128 + 8 * c;
  *(float4*)(go) = a0;
  *(float4*)(go + 4) = a1;
}

// ---------------- GEMM2: h2(bf16) = g @ W2  (100k x 128 x 40) ----------------

__global__ __launch_bounds__(256) void k_gemm2(const float* __restrict__ g,
                                               const float* __restrict__ W2,
                                               unsigned* __restrict__ h2b) {
  __shared__ float Ws[128 * 40];
  __shared__ float Xs[32 * 132];
  const int t = threadIdx.x;
  const int row0 = blockIdx.x * 32;
  const int c4 = t & 15;
  const int rg = t >> 4;
#pragma unroll
  for (int j = 0; j < 5; ++j) {
    int q = t + 256 * j;
    int k = q / 10, cc = q % 10;
    *(float4*)(Ws + k * 40 + 4 * cc) = *(const float4*)(W2 + k * 40 + 4 * cc);
  }
#pragma unroll
  for (int j = 0; j < 4; ++j) {
    int q = t + 256 * j;
    int r = q >> 5, kc = q & 31;
    *(float4*)(Xs + r * 132 + 4 * kc) =
        *(const float4*)(g + (size_t)(row0 + r) * 128 + 4 * kc);
  }
  __syncthreads();
  if (c4 < 10) {
    float4 a0 = make_float4(0.f, 0.f, 0.f, 0.f);
    float4 a1 = make_float4(0.f, 0.f, 0.f, 0.f);
#pragma unroll 4
    for (int kq = 0; kq < 32; ++kq) {
      float4 x0 = *(const float4*)(Xs + (rg * 2) * 132 + 4 * kq);
      float4 x1 = *(const float4*)(Xs + (rg * 2 + 1) * 132 + 4 * kq);
#pragma unroll
      for (int kk = 0; kk < 4; ++kk) {
        float4 wv = *(const float4*)(Ws + (kq * 4 + kk) * 40 + 4 * c4);
        float xc0 = ((const float*)&x0)[kk];
        float xc1 = ((const float*)&x1)[kk];
        a0.x = fmaf(xc0, wv.x, a0.x);
        a0.y = fmaf(xc0, wv.y, a0.y);
        a0.z = fmaf(xc0, wv.z, a0.z);
        a0.w = fmaf(xc0, wv.w, a0.w);
        a1.x = fmaf(xc1, wv.x, a1.x);
        a1.y = fmaf(xc1, wv.y, a1.y);
        a1.z = fmaf(xc1, wv.z, a1.z);
        a1.w = fmaf(xc1, wv.w, a1.w);
      }
    }
    uint2 p0, p1;
    p0.x = pack_bf16x2(a0.x, a0.y); p0.y = pack_bf16x2(a0.z, a0.w);
    p1.x = pack_bf16x2(a1.x, a1.y); p1.y = pack_bf16x2(a1.z, a1.w);
    *(uint2*)(h2b + (size_t)(row0 + rg * 2) * 20 + 2 * c4) = p0;
    *(uint2*)(h2b + (size_t)(row0 + rg * 2 + 1) * 20 + 2 * c4) = p1;
  }
}

// ---------------- AGG2: out[n] = ii[n] * sum h2[src]  (bf16 gather, 40 ch) ----------------
// 16-lane groups, lanes 0..9 load uint2 (4 bf16) each.

__global__ __launch_bounds__(256) void k_agg2(const unsigned* __restrict__ h2b,
                                              const int* __restrict__ csr_src,
                                              const int* __restrict__ row_ptr,
                                              const float* __restrict__ ii,
                                              float* __restrict__ out) {
  const int t = threadIdx.x;
  const int node = blockIdx.x * 16 + (t >> 4);
  const int c = t & 15;
  if (c < 10) {
    const int beg = row_ptr[node];
    const int end = row_ptr[node + 1];
    float4 acc = make_float4(0.f, 0.f, 0.f, 0.f);
    for (int j = beg; j < end; ++j) {
      int s = csr_src[j];
      uint2 v = *(const uint2*)(h2b + (size_t)s * 20 + 2 * c);
      acc.x += bf_lo(v.x); acc.y += bf_hi(v.x);
      acc.z += bf_lo(v.y); acc.w += bf_hi(v.y);
    }
    float sc = ii[node];
    acc.x *= sc; acc.y *= sc; acc.z *= sc; acc.w *= sc;
    *(float4*)(out + (size_t)node * 40 + 4 * c) = acc;
  }
}

// ---------------- launch ----------------

extern "C" void kernel_launch(void* const* d_in, const int* in_sizes, int n_in,
                              void* d_out, int out_size, void* d_ws, size_t ws_size,
                              hipStream_t stream) {
  const float* x  = (const float*)d_in[0];
  const int* ei   = (const int*)d_in[1];
  const float* W1 = (const float*)d_in[2];
  const float* W2 = (const float*)d_in[3];
  const int* src = ei;
  const int* dst = ei + N_EDGES;
  float* out = (float*)d_out;

  char* p = (char*)d_ws;
  auto alloc = [&](size_t b) -> void* {
    char* r = p;
    p += (b + 255) & ~(size_t)255;
    return (void*)r;
  };
  unsigned* deg_out = (unsigned*)alloc((size_t)N_NODES * 4);
  float* oi         = (float*)alloc((size_t)N_NODES * 4);
  float* ii         = (float*)alloc((size_t)N_NODES * 4);
  float* coi        = (float*)alloc((size_t)N_NODES * 4);
  int* row_ptr      = (int*)alloc((size_t)(N_NODES + 1) * 4);
  unsigned* histG   = (unsigned*)alloc((size_t)NBUCK * NCHUNK * 4);
  unsigned* btot    = (unsigned*)alloc((size_t)NBUCK * 4);
  int* bbase        = (int*)alloc((size_t)(NBUCK + 1) * 4);
  int* ebuf         = (int*)alloc((size_t)N_EDGES * 4);
  int* csr_src      = (int*)alloc((size_t)N_EDGES * 4);
  unsigned* h1b     = (unsigned*)alloc((size_t)N_NODES * 64 * 4);  // bf16 x128
  float* g          = (float*)alloc((size_t)N_NODES * 128 * 4);
  unsigned* h2b     = (unsigned*)alloc((size_t)N_NODES * 20 * 4);  // bf16 x40

  hipMemsetAsync(deg_out, 0, (size_t)N_NODES * 4, stream);
  k_degree_src<<<N_EDGES / 256, 256, 0, stream>>>(src, deg_out);
  k_isqrt_o<<<(N_NODES + 255) / 256, 256, 0, stream>>>(deg_out, oi);
  k_hist<<<NCHUNK, 256, 0, stream>>>(dst, histG);
  k_offs<<<(NBUCK + 3) / 4, 256, 0, stream>>>(histG, btot);
  k_bscan<<<1, 1024, 0, stream>>>(btot, bbase, row_ptr);
  k_part<<<NCHUNK, 256, 0, stream>>>(src, dst, histG, bbase, ebuf);
  k_bfill2<<<NBUCK, 256, 0, stream>>>(ebuf, bbase, oi, row_ptr, csr_src, ii, coi);
  k_gemm1<<<N_NODES / 32, 256, 0, stream>>>(x, oi, W1, h1b);
  k_agg1<<<N_NODES / 16, 256, 0, stream>>>(h1b, csr_src, row_ptr, coi, g);
  k_gemm2<<<N_NODES / 32, 256, 0, stream>>>(g, W2, h2b);
  k_agg2<<<N_NODES / 16, 256, 0, stream>>>(h2b, csr_src, row_ptr, ii, out);
}

// Round 5
// 327.479 us; speedup vs baseline: 2.6787x; 1.2762x over previous
//
#include <hip/hip_runtime.h>

#define N_NODES 100000
#define N_EDGES 1600000
#define BSHIFT 7
#define NBUCK 782     // ceil(N_NODES/128)
#define NCHUNK 1000
#define CH 1600       // N_EDGES / NCHUNK exactly

typedef __attribute__((ext_vector_type(8))) short bf16x8;
typedef __attribute__((ext_vector_type(4))) float f32x4;

// bf16 helpers (RTNE pack; unpack = shift to high half)
__device__ __forceinline__ unsigned pack_bf16x2(float a, float b) {
  unsigned ua = __float_as_uint(a);
  unsigned ub = __float_as_uint(b);
  ua = ua + 0x7fffu + ((ua >> 16) & 1u);
  ub = ub + 0x7fffu + ((ub >> 16) & 1u);
  return (ua >> 16) | (ub & 0xffff0000u);
}
__device__ __forceinline__ unsigned short bf16u(float f) {
  unsigned u = __float_as_uint(f);
  u = u + 0x7fffu + ((u >> 16) & 1u);
  return (unsigned short)(u >> 16);
}
__device__ __forceinline__ float bf_lo(unsigned u) { return __uint_as_float(u << 16); }
__device__ __forceinline__ float bf_hi(unsigned u) { return __uint_as_float(u & 0xffff0000u); }

// ---------------- src out-degree (for oi) ----------------

__global__ __launch_bounds__(256) void k_degree_src(const int* __restrict__ src,
                                                    unsigned* __restrict__ dout) {
  int e = blockIdx.x * 256 + threadIdx.x;
  if (e < N_EDGES) atomicAdd(&dout[src[e]], 1u);
}

__global__ __launch_bounds__(256) void k_isqrt_o(const unsigned* __restrict__ dout,
                                                 float* __restrict__ oi) {
  int i = blockIdx.x * 256 + threadIdx.x;
  if (i < N_NODES) {
    unsigned a = dout[i]; if (a < 1u) a = 1u;
    oi[i] = rsqrtf((float)a);
  }
}

// ---------------- weight prep: transpose + bf16 (once) ----------------
// Wt1[n][k] = bf16(W1[k][n]), 128x128. Wt2[n][k] = bf16(W2[k][n]), 48x128 (zeros n>=40).

__global__ __launch_bounds__(256) void k_prepw(const float* __restrict__ W1,
                                               const float* __restrict__ W2,
                                               unsigned short* __restrict__ Wt1,
                                               unsigned short* __restrict__ Wt2) {
  int t = blockIdx.x * 256 + threadIdx.x;
  if (t < 128 * 128) {
    int n = t >> 7, k = t & 127;
    Wt1[n * 128 + k] = bf16u(W1[k * 128 + n]);
  }
  if (t < 48 * 128) {
    int n = t >> 7, k = t & 127;
    float v = (n < 40) ? W2[k * 40 + n] : 0.f;
    Wt2[n * 128 + k] = bf16u(v);
  }
}

// ---------------- deterministic counting-sort partition (no global atomics) ----------------

__global__ __launch_bounds__(256) void k_hist(const int* __restrict__ dst,
                                              unsigned* __restrict__ histG) {
  __shared__ unsigned h[NBUCK];
  const int t = threadIdx.x, j = blockIdx.x;
  for (int i = t; i < NBUCK; i += 256) h[i] = 0u;
  __syncthreads();
  const int e0 = j * CH;
  for (int e = e0 + t; e < e0 + CH; e += 256)
    atomicAdd(&h[(unsigned)dst[e] >> BSHIFT], 1u);
  __syncthreads();
  for (int i = t; i < NBUCK; i += 256) histG[(size_t)i * NCHUNK + j] = h[i];
}

// one block per bucket: exclusive scan of its NCHUNK chunk-counts (in place) + total
__global__ __launch_bounds__(256) void k_offs(unsigned* __restrict__ histG,
                                              unsigned* __restrict__ btot) {
  __shared__ unsigned sd[256];
  const int bu = blockIdx.x, t = threadIdx.x;
  unsigned* col = histG + (size_t)bu * NCHUNK;
  unsigned v[4], s = 0;
#pragma unroll
  for (int i = 0; i < 4; ++i) {
    int idx = t * 4 + i;
    v[i] = (idx < NCHUNK) ? col[idx] : 0u;
    s += v[i];
  }
  sd[t] = s;
  __syncthreads();
  for (int d = 1; d < 256; d <<= 1) {
    unsigned a = (t >= d) ? sd[t - d] : 0u;
    __syncthreads();
    sd[t] += a;
    __syncthreads();
  }
  unsigned run = sd[t] - s;  // exclusive
#pragma unroll
  for (int i = 0; i < 4; ++i) {
    int idx = t * 4 + i;
    if (idx < NCHUNK) { unsigned tv = v[i]; col[idx] = run; run += tv; }
  }
  if (t == 255) btot[bu] = run;
}

__global__ __launch_bounds__(1024) void k_bscan(const unsigned* __restrict__ btot,
                                                int* __restrict__ bbase,
                                                int* __restrict__ row_ptr) {
  __shared__ unsigned sd[1024];
  const int t = threadIdx.x;
  unsigned v = (t < NBUCK) ? btot[t] : 0u;
  sd[t] = v;
  __syncthreads();
  for (int d = 1; d < 1024; d <<= 1) {
    unsigned a = (t >= d) ? sd[t - d] : 0u;
    __syncthreads();
    sd[t] += a;
    __syncthreads();
  }
  if (t < NBUCK) bbase[t] = (int)(sd[t] - v);
  if (t == 0) { bbase[NBUCK] = N_EDGES; row_ptr[N_NODES] = N_EDGES; }
}

__global__ __launch_bounds__(256) void k_part(const int* __restrict__ src,
                                              const int* __restrict__ dst,
                                              const unsigned* __restrict__ histG,
                                              const int* __restrict__ bbase,
                                              int* __restrict__ ebuf) {
  __shared__ unsigned lcur[NBUCK];
  __shared__ int lbase[NBUCK];
  const int t = threadIdx.x, j = blockIdx.x;
  for (int i = t; i < NBUCK; i += 256) {
    lcur[i] = histG[(size_t)i * NCHUNK + j];
    lbase[i] = bbase[i];
  }
  __syncthreads();
  const int e0 = j * CH;
  for (int e = e0 + t; e < e0 + CH; e += 256) {
    int d = dst[e], s = src[e];
    int bu = (unsigned)d >> BSHIFT;
    unsigned r = atomicAdd(&lcur[bu], 1u);
    ebuf[lbase[bu] + (int)r] = ((d & 127) << 17) | s;
  }
}

__global__ __launch_bounds__(256) void k_bfill2(const int* __restrict__ ebuf,
                                                const int* __restrict__ bbase,
                                                const float* __restrict__ oi,
                                                int* __restrict__ row_ptr,
                                                int* __restrict__ csr_src,
                                                float* __restrict__ ii,
                                                float* __restrict__ coi) {
  __shared__ unsigned cnt[128];
  __shared__ int start[128];
  const int b = blockIdx.x, t = threadIdx.x;
  const int node0 = b << BSHIFT;
  const int base = bbase[b], end = bbase[b + 1];
  if (t < 128) cnt[t] = 0u;
  __syncthreads();
  for (int j = base + t; j < end; j += 256)
    atomicAdd(&cnt[(unsigned)ebuf[j] >> 17], 1u);
  __syncthreads();
  if (t == 0) {
    int r = 0;
    for (int i = 0; i < 128; ++i) { start[i] = r; r += (int)cnt[i]; }
  }
  __syncthreads();
  if (t < 128) {
    int n = node0 + t;
    if (n < N_NODES) {
      row_ptr[n] = base + start[t];
      unsigned c = cnt[t]; if (c < 1u) c = 1u;
      float iv = rsqrtf((float)c);
      ii[n] = iv;
      coi[n] = iv * oi[n];  // relu(ii*agg)*oi == (ii*oi)*relu(agg)
    }
  }
  __syncthreads();
  if (t < 128) cnt[t] = (unsigned)start[t];
  __syncthreads();
  for (int j = base + t; j < end; j += 256) {
    int pk = ebuf[j];
    unsigned dn = (unsigned)pk >> 17;
    unsigned slot = atomicAdd(&cnt[dn], 1u);
    csr_src[base + (int)slot] = pk & 0x1FFFF;
  }
}

// ---------------- GEMM1 (MFMA bf16): h1b = bf16((x*oi) @ W1), 100k x 128 x 128 ----------------
// block = 256 thr = 4 waves; 64 rows/block; wave w: rows w*16..w*16+15, all 128 cols.
// LDS: Xs 64x(128+8pad) bf16, Ws 128x(128+8) bf16 (Wt1[n][k]).

#define LPAD 136  // ushort stride (272 B = 17*16, keeps 16B alignment; bank stride 68%32=4 -> 2-way)

__global__ __launch_bounds__(256) void k_gemm1(const float* __restrict__ x,
                                               const float* __restrict__ oi,
                                               const unsigned short* __restrict__ Wt1,
                                               unsigned short* __restrict__ h1b) {
  __shared__ unsigned short Xs[64 * LPAD];
  __shared__ unsigned short Ws[128 * LPAD];
  const int t = threadIdx.x;
  const int row0 = blockIdx.x * 64;
#pragma unroll
  for (int j = 0; j < 8; ++j) {        // stage Wt1: 2048 chunks of 8 ushorts
    int q = t + 256 * j;
    int n = q >> 4, c = q & 15;
    *(uint4*)(Ws + n * LPAD + c * 8) = *(const uint4*)(Wt1 + n * 128 + c * 8);
  }
#pragma unroll
  for (int j = 0; j < 4; ++j) {        // stage X: 64 rows x 16 chunks of 8
    int q = t + 256 * j;
    int r = q >> 4, c = q & 15;
    int gr = row0 + r; if (gr >= N_NODES) gr = N_NODES - 1;
    const float* xp = x + (size_t)gr * 128 + c * 8;
    float4 v0 = *(const float4*)(xp);
    float4 v1 = *(const float4*)(xp + 4);
    float s = oi[gr];
    uint4 pk;
    pk.x = pack_bf16x2(v0.x * s, v0.y * s);
    pk.y = pack_bf16x2(v0.z * s, v0.w * s);
    pk.z = pack_bf16x2(v1.x * s, v1.y * s);
    pk.w = pack_bf16x2(v1.z * s, v1.w * s);
    *(uint4*)(Xs + r * LPAD + c * 8) = pk;
  }
  __syncthreads();
  const int w = t >> 6, lane = t & 63;
  const int m = lane & 15;
  const int q8 = (lane >> 4) * 8;
  f32x4 acc[8];
#pragma unroll
  for (int i = 0; i < 8; ++i) acc[i] = (f32x4){0.f, 0.f, 0.f, 0.f};
  const unsigned short* xrow = Xs + (w * 16 + m) * LPAD;
#pragma unroll
  for (int ks = 0; ks < 4; ++ks) {
    bf16x8 a = *(const bf16x8*)(xrow + ks * 32 + q8);
#pragma unroll
    for (int ct = 0; ct < 8; ++ct) {
      bf16x8 b = *(const bf16x8*)(Ws + (ct * 16 + m) * LPAD + ks * 32 + q8);
      acc[ct] = __builtin_amdgcn_mfma_f32_16x16x32_bf16(a, b, acc[ct], 0, 0, 0);
    }
  }
  const int rbase = row0 + w * 16 + (lane >> 4) * 4;
#pragma unroll
  for (int ct = 0; ct < 8; ++ct) {
    int coln = ct * 16 + m;
#pragma unroll
    for (int r = 0; r < 4; ++r) {
      int grow = rbase + r;
      if (grow < N_NODES) h1b[(size_t)grow * 128 + coln] = bf16u(acc[ct][r]);
    }
  }
}

// ---------------- AGG1: g = bf16(coi * relu(sum h1[src]))  (MLP x4 gather) ----------------
// 16 lanes/node (8 ch each), 16 nodes/block.

__global__ __launch_bounds__(256) void k_agg1(const unsigned short* __restrict__ h1b,
                                              const int* __restrict__ csr_src,
                                              const int* __restrict__ row_ptr,
                                              const float* __restrict__ coi,
                                              unsigned short* __restrict__ g) {
  const int t = threadIdx.x;
  const int node = blockIdx.x * 16 + (t >> 4);
  const int c = t & 15;
  const int beg = row_ptr[node];
  const int end = row_ptr[node + 1];
  float4 a0 = make_float4(0.f, 0.f, 0.f, 0.f);
  float4 a1 = make_float4(0.f, 0.f, 0.f, 0.f);
  int j = beg;
  for (; j + 4 <= end; j += 4) {
    int s0 = csr_src[j], s1 = csr_src[j + 1], s2 = csr_src[j + 2], s3 = csr_src[j + 3];
    uint4 v0 = *(const uint4*)(h1b + (size_t)s0 * 128 + 8 * c);
    uint4 v1 = *(const uint4*)(h1b + (size_t)s1 * 128 + 8 * c);
    uint4 v2 = *(const uint4*)(h1b + (size_t)s2 * 128 + 8 * c);
    uint4 v3 = *(const uint4*)(h1b + (size_t)s3 * 128 + 8 * c);
    a0.x += bf_lo(v0.x); a0.y += bf_hi(v0.x); a0.z += bf_lo(v0.y); a0.w += bf_hi(v0.y);
    a1.x += bf_lo(v0.z); a1.y += bf_hi(v0.z); a1.z += bf_lo(v0.w); a1.w += bf_hi(v0.w);
    a0.x += bf_lo(v1.x); a0.y += bf_hi(v1.x); a0.z += bf_lo(v1.y); a0.w += bf_hi(v1.y);
    a1.x += bf_lo(v1.z); a1.y += bf_hi(v1.z); a1.z += bf_lo(v1.w); a1.w += bf_hi(v1.w);
    a0.x += bf_lo(v2.x); a0.y += bf_hi(v2.x); a0.z += bf_lo(v2.y); a0.w += bf_hi(v2.y);
    a1.x += bf_lo(v2.z); a1.y += bf_hi(v2.z); a1.z += bf_lo(v2.w); a1.w += bf_hi(v2.w);
    a0.x += bf_lo(v3.x); a0.y += bf_hi(v3.x); a0.z += bf_lo(v3.y); a0.w += bf_hi(v3.y);
    a1.x += bf_lo(v3.z); a1.y += bf_hi(v3.z); a1.z += bf_lo(v3.w); a1.w += bf_hi(v3.w);
  }
  for (; j < end; ++j) {
    int s = csr_src[j];
    uint4 v = *(const uint4*)(h1b + (size_t)s * 128 + 8 * c);
    a0.x += bf_lo(v.x); a0.y += bf_hi(v.x); a0.z += bf_lo(v.y); a0.w += bf_hi(v.y);
    a1.x += bf_lo(v.z); a1.y += bf_hi(v.z); a1.z += bf_lo(v.w); a1.w += bf_hi(v.w);
  }
  float sc = coi[node];
  uint4 pk;
  pk.x = pack_bf16x2(fmaxf(a0.x, 0.f) * sc, fmaxf(a0.y, 0.f) * sc);
  pk.y = pack_bf16x2(fmaxf(a0.z, 0.f) * sc, fmaxf(a0.w, 0.f) * sc);
  pk.z = pack_bf16x2(fmaxf(a1.x, 0.f) * sc, fmaxf(a1.y, 0.f) * sc);
  pk.w = pack_bf16x2(fmaxf(a1.z, 0.f) * sc, fmaxf(a1.w, 0.f) * sc);
  *(uint4*)(g + (size_t)node * 128 + 8 * c) = pk;
}

// ---------------- GEMM2 (MFMA bf16): h2b = bf16(g @ W2), 100k x 128 x 40 (N padded 48) ----------------

__global__ __launch_bounds__(256) void k_gemm2(const unsigned short* __restrict__ gb,
                                               const unsigned short* __restrict__ Wt2,
                                               unsigned short* __restrict__ h2b) {
  __shared__ unsigned short Gs[64 * LPAD];
  __shared__ unsigned short Ws[48 * LPAD];
  const int t = threadIdx.x;
  const int row0 = blockIdx.x * 64;
#pragma unroll
  for (int j = 0; j < 3; ++j) {        // stage Wt2: 768 chunks
    int q = t + 256 * j;
    int n = q >> 4, c = q & 15;
    *(uint4*)(Ws + n * LPAD + c * 8) = *(const uint4*)(Wt2 + n * 128 + c * 8);
  }
#pragma unroll
  for (int j = 0; j < 4; ++j) {        // stage G: 1024 chunks
    int q = t + 256 * j;
    int r = q >> 4, c = q & 15;
    int gr = row0 + r; if (gr >= N_NODES) gr = N_NODES - 1;
    *(uint4*)(Gs + r * LPAD + c * 8) = *(const uint4*)(gb + (size_t)gr * 128 + c * 8);
  }
  __syncthreads();
  const int w = t >> 6, lane = t & 63;
  const int m = lane & 15;
  const int q8 = (lane >> 4) * 8;
  f32x4 acc[3];
#pragma unroll
  for (int i = 0; i < 3; ++i) acc[i] = (f32x4){0.f, 0.f, 0.f, 0.f};
  const unsigned short* grow_p = Gs + (w * 16 + m) * LPAD;
#pragma unroll
  for (int ks = 0; ks < 4; ++ks) {
    bf16x8 a = *(const bf16x8*)(grow_p + ks * 32 + q8);
#pragma unroll
    for (int ct = 0; ct < 3; ++ct) {
      bf16x8 b = *(const bf16x8*)(Ws + (ct * 16 + m) * LPAD + ks * 32 + q8);
      acc[ct] = __builtin_amdgcn_mfma_f32_16x16x32_bf16(a, b, acc[ct], 0, 0, 0);
    }
  }
  const int rbase = row0 + w * 16 + (lane >> 4) * 4;
#pragma unroll
  for (int ct = 0; ct < 3; ++ct) {
    int coln = ct * 16 + m;
    if (coln < 40) {
#pragma unroll
      for (int r = 0; r < 4; ++r) {
        int grow = rbase + r;
        if (grow < N_NODES) h2b[(size_t)grow * 40 + coln] = bf16u(acc[ct][r]);
      }
    }
  }
}

// ---------------- AGG2: out = ii * sum h2[src]  (MLP x4 gather, 40 ch fp32 out) ----------------

__global__ __launch_bounds__(256) void k_agg2(const unsigned short* __restrict__ h2b,
                                              const int* __restrict__ csr_src,
                                              const int* __restrict__ row_ptr,
                                              const float* __restrict__ ii,
                                              float* __restrict__ out) {
  const int t = threadIdx.x;
  const int node = blockIdx.x * 16 + (t >> 4);
  const int c = t & 15;
  if (c >= 10) return;
  const int beg = row_ptr[node];
  const int end = row_ptr[node + 1];
  float4 acc = make_float4(0.f, 0.f, 0.f, 0.f);
  int j = beg;
  for (; j + 4 <= end; j += 4) {
    int s0 = csr_src[j], s1 = csr_src[j + 1], s2 = csr_src[j + 2], s3 = csr_src[j + 3];
    uint2 v0 = *(const uint2*)(h2b + (size_t)s0 * 40 + 4 * c);
    uint2 v1 = *(const uint2*)(h2b + (size_t)s1 * 40 + 4 * c);
    uint2 v2 = *(const uint2*)(h2b + (size_t)s2 * 40 + 4 * c);
    uint2 v3 = *(const uint2*)(h2b + (size_t)s3 * 40 + 4 * c);
    acc.x += bf_lo(v0.x); acc.y += bf_hi(v0.x); acc.z += bf_lo(v0.y); acc.w += bf_hi(v0.y);
    acc.x += bf_lo(v1.x); acc.y += bf_hi(v1.x); acc.z += bf_lo(v1.y); acc.w += bf_hi(v1.y);
    acc.x += bf_lo(v2.x); acc.y += bf_hi(v2.x); acc.z += bf_lo(v2.y); acc.w += bf_hi(v2.y);
    acc.x += bf_lo(v3.x); acc.y += bf_hi(v3.x); acc.z += bf_lo(v3.y); acc.w += bf_hi(v3.y);
  }
  for (; j < end; ++j) {
    int s = csr_src[j];
    uint2 v = *(const uint2*)(h2b + (size_t)s * 40 + 4 * c);
    acc.x += bf_lo(v.x); acc.y += bf_hi(v.x); acc.z += bf_lo(v.y); acc.w += bf_hi(v.y);
  }
  float sc = ii[node];
  acc.x *= sc; acc.y *= sc; acc.z *= sc; acc.w *= sc;
  *(float4*)(out + (size_t)node * 40 + 4 * c) = acc;
}

// ---------------- launch ----------------

extern "C" void kernel_launch(void* const* d_in, const int* in_sizes, int n_in,
                              void* d_out, int out_size, void* d_ws, size_t ws_size,
                              hipStream_t stream) {
  const float* x  = (const float*)d_in[0];
  const int* ei   = (const int*)d_in[1];
  const float* W1 = (const float*)d_in[2];
  const float* W2 = (const float*)d_in[3];
  const int* src = ei;
  const int* dst = ei + N_EDGES;
  float* out = (float*)d_out;

  char* p = (char*)d_ws;
  auto alloc = [&](size_t b) -> void* {
    char* r = p;
    p += (b + 255) & ~(size_t)255;
    return (void*)r;
  };
  unsigned* deg_out    = (unsigned*)alloc((size_t)N_NODES * 4);
  float* oi            = (float*)alloc((size_t)N_NODES * 4);
  float* ii            = (float*)alloc((size_t)N_NODES * 4);
  float* coi           = (float*)alloc((size_t)N_NODES * 4);
  int* row_ptr         = (int*)alloc((size_t)(N_NODES + 1) * 4);
  unsigned* histG      = (unsigned*)alloc((size_t)NBUCK * NCHUNK * 4);
  unsigned* btot       = (unsigned*)alloc((size_t)NBUCK * 4);
  int* bbase           = (int*)alloc((size_t)(NBUCK + 1) * 4);
  int* ebuf            = (int*)alloc((size_t)N_EDGES * 4);
  int* csr_src         = (int*)alloc((size_t)N_EDGES * 4);
  unsigned short* Wt1  = (unsigned short*)alloc((size_t)128 * 128 * 2);
  unsigned short* Wt2  = (unsigned short*)alloc((size_t)48 * 128 * 2);
  unsigned short* h1b  = (unsigned short*)alloc((size_t)N_NODES * 128 * 2);
  unsigned short* g    = (unsigned short*)alloc((size_t)N_NODES * 128 * 2);
  unsigned short* h2b  = (unsigned short*)alloc((size_t)N_NODES * 40 * 2);

  hipMemsetAsync(deg_out, 0, (size_t)N_NODES * 4, stream);
  k_degree_src<<<N_EDGES / 256, 256, 0, stream>>>(src, deg_out);
  k_isqrt_o<<<(N_NODES + 255) / 256, 256, 0, stream>>>(deg_out, oi);
  k_prepw<<<64, 256, 0, stream>>>(W1, W2, Wt1, Wt2);
  k_hist<<<NCHUNK, 256, 0, stream>>>(dst, histG);
  k_offs<<<NBUCK, 256, 0, stream>>>(histG, btot);
  k_bscan<<<1, 1024, 0, stream>>>(btot, bbase, row_ptr);
  k_part<<<NCHUNK, 256, 0, stream>>>(src, dst, histG, bbase, ebuf);
  k_bfill2<<<NBUCK, 256, 0, stream>>>(ebuf, bbase, oi, row_ptr, csr_src, ii, coi);
  k_gemm1<<<(N_NODES + 63) / 64, 256, 0, stream>>>(x, oi, Wt1, h1b);
  k_agg1<<<N_NODES / 16, 256, 0, stream>>>(h1b, csr_src, row_ptr, coi, g);
  k_gemm2<<<(N_NODES + 63) / 64, 256, 0, stream>>>(g, Wt2, h2b);
  k_agg2<<<N_NODES / 16, 256, 0, stream>>>(h2b, csr_src, row_ptr, ii, out);
}

// Round 6
// 295.873 us; speedup vs baseline: 2.9648x; 1.1068x over previous
//
#include <hip/hip_runtime.h>

#define N_NODES 100000
#define N_EDGES 1600000
#define BSHIFT 7
#define NBUCK 782     // ceil(N_NODES/128)
#define NCHUNK 1000
#define CH 1600       // N_EDGES / NCHUNK exactly

typedef __attribute__((ext_vector_type(8))) short bf16x8;
typedef __attribute__((ext_vector_type(4))) float f32x4;

// bf16 helpers (RTNE pack; unpack = shift to high half)
__device__ __forceinline__ unsigned pack_bf16x2(float a, float b) {
  unsigned ua = __float_as_uint(a);
  unsigned ub = __float_as_uint(b);
  ua = ua + 0x7fffu + ((ua >> 16) & 1u);
  ub = ub + 0x7fffu + ((ub >> 16) & 1u);
  return (ua >> 16) | (ub & 0xffff0000u);
}
__device__ __forceinline__ unsigned short bf16u(float f) {
  unsigned u = __float_as_uint(f);
  u = u + 0x7fffu + ((u >> 16) & 1u);
  return (unsigned short)(u >> 16);
}
__device__ __forceinline__ float bf_lo(unsigned u) { return __uint_as_float(u << 16); }
__device__ __forceinline__ float bf_hi(unsigned u) { return __uint_as_float(u & 0xffff0000u); }

// ---------------- weight prep: transpose + bf16 (once) ----------------

__global__ __launch_bounds__(256) void k_prepw(const float* __restrict__ W1,
                                               const float* __restrict__ W2,
                                               unsigned short* __restrict__ Wt1,
                                               unsigned short* __restrict__ Wt2) {
  int t = blockIdx.x * 256 + threadIdx.x;
  if (t < 128 * 128) {
    int n = t >> 7, k = t & 127;
    Wt1[n * 128 + k] = bf16u(W1[k * 128 + n]);
  }
  if (t < 48 * 128) {
    int n = t >> 7, k = t & 127;
    float v = (n < 40) ? W2[k * 40 + n] : 0.f;
    Wt2[n * 128 + k] = bf16u(v);
  }
}

// ---------------- counting-sort partition, BOTH src and dst (no global atomics) ----------------
// Pass 1: per-chunk LDS histograms over 782 buckets for dst AND src.

__global__ __launch_bounds__(256) void k_hist(const int* __restrict__ src,
                                              const int* __restrict__ dst,
                                              unsigned* __restrict__ histGd,
                                              unsigned* __restrict__ histGs) {
  __shared__ unsigned hd[NBUCK];
  __shared__ unsigned hs[NBUCK];
  const int t = threadIdx.x, j = blockIdx.x;
  for (int i = t; i < NBUCK; i += 256) { hd[i] = 0u; hs[i] = 0u; }
  __syncthreads();
  const int e0 = j * CH;
  for (int e = e0 + t; e < e0 + CH; e += 256) {
    atomicAdd(&hd[(unsigned)dst[e] >> BSHIFT], 1u);
    atomicAdd(&hs[(unsigned)src[e] >> BSHIFT], 1u);
  }
  __syncthreads();
  for (int i = t; i < NBUCK; i += 256) {
    histGd[(size_t)i * NCHUNK + j] = hd[i];
    histGs[(size_t)i * NCHUNK + j] = hs[i];
  }
}

// Pass 2: block per (bucket, stream) — exclusive scan of NCHUNK chunk-counts in place + total.
__global__ __launch_bounds__(256) void k_offs(unsigned* __restrict__ histGd,
                                              unsigned* __restrict__ histGs,
                                              unsigned* __restrict__ btot) {
  __shared__ unsigned sd[256];
  const int bu = blockIdx.x, t = threadIdx.x;
  unsigned* col = (bu < NBUCK) ? histGd + (size_t)bu * NCHUNK
                               : histGs + (size_t)(bu - NBUCK) * NCHUNK;
  unsigned v[4], s = 0;
#pragma unroll
  for (int i = 0; i < 4; ++i) {
    int idx = t * 4 + i;
    v[i] = (idx < NCHUNK) ? col[idx] : 0u;
    s += v[i];
  }
  sd[t] = s;
  __syncthreads();
  for (int d = 1; d < 256; d <<= 1) {
    unsigned a = (t >= d) ? sd[t - d] : 0u;
    __syncthreads();
    sd[t] += a;
    __syncthreads();
  }
  unsigned run = sd[t] - s;
#pragma unroll
  for (int i = 0; i < 4; ++i) {
    int idx = t * 4 + i;
    if (idx < NCHUNK) { unsigned tv = v[i]; col[idx] = run; run += tv; }
  }
  if (t == 255) btot[bu] = run;
}

// Pass 3: two blocks — scan dst totals -> bbase, src totals -> sbase.
__global__ __launch_bounds__(1024) void k_bscan2(const unsigned* __restrict__ btot,
                                                 int* __restrict__ bbase,
                                                 int* __restrict__ sbase,
                                                 int* __restrict__ row_ptr) {
  __shared__ unsigned sd[1024];
  const int t = threadIdx.x;
  const unsigned* bt = btot + (blockIdx.x ? NBUCK : 0);
  int* ob = blockIdx.x ? sbase : bbase;
  unsigned v = (t < NBUCK) ? bt[t] : 0u;
  sd[t] = v;
  __syncthreads();
  for (int d = 1; d < 1024; d <<= 1) {
    unsigned a = (t >= d) ? sd[t - d] : 0u;
    __syncthreads();
    sd[t] += a;
    __syncthreads();
  }
  if (t < NBUCK) ob[t] = (int)(sd[t] - v);
  if (t == 0) {
    ob[NBUCK] = N_EDGES;
    if (blockIdx.x == 0) row_ptr[N_NODES] = N_EDGES;
  }
}

// Pass 4: scatter. dst stream: packed (dst&127)<<17|src into ebuf (bucket-ordered).
// src stream: 1-byte residue s&127 into ebuf2 (bucket-ordered) — for degree counting.

__global__ __launch_bounds__(256) void k_part(const int* __restrict__ src,
                                              const int* __restrict__ dst,
                                              const unsigned* __restrict__ histGd,
                                              const unsigned* __restrict__ histGs,
                                              const int* __restrict__ bbase,
                                              const int* __restrict__ sbase,
                                              int* __restrict__ ebuf,
                                              unsigned char* __restrict__ ebuf2) {
  __shared__ unsigned lcD[NBUCK];
  __shared__ unsigned lcS[NBUCK];
  __shared__ int lbD[NBUCK];
  __shared__ int lbS[NBUCK];
  const int t = threadIdx.x, j = blockIdx.x;
  for (int i = t; i < NBUCK; i += 256) {
    lcD[i] = histGd[(size_t)i * NCHUNK + j];
    lbD[i] = bbase[i];
    lcS[i] = histGs[(size_t)i * NCHUNK + j];
    lbS[i] = sbase[i];
  }
  __syncthreads();
  const int e0 = j * CH;
  for (int e = e0 + t; e < e0 + CH; e += 256) {
    int d = dst[e], s = src[e];
    int bd = (unsigned)d >> BSHIFT;
    unsigned rd = atomicAdd(&lcD[bd], 1u);
    ebuf[lbD[bd] + (int)rd] = ((d & 127) << 17) | s;
    int bs = (unsigned)s >> BSHIFT;
    unsigned rs = atomicAdd(&lcS[bs], 1u);
    ebuf2[lbS[bs] + (int)rs] = (unsigned char)(s & 127);
  }
}

// Pass 5a: src-degree per bucket -> oi (LDS count, no global atomics).
__global__ __launch_bounds__(256) void k_count_src(const unsigned char* __restrict__ ebuf2,
                                                   const int* __restrict__ sbase,
                                                   float* __restrict__ oi) {
  __shared__ unsigned cnt[128];
  const int b = blockIdx.x, t = threadIdx.x;
  if (t < 128) cnt[t] = 0u;
  __syncthreads();
  const int base = sbase[b], end = sbase[b + 1];
  for (int j = base + t; j < end; j += 256)
    atomicAdd(&cnt[ebuf2[j]], 1u);
  __syncthreads();
  if (t < 128) {
    int n = (b << BSHIFT) + t;
    if (n < N_NODES) {
      unsigned c = cnt[t]; if (c < 1u) c = 1u;
      oi[n] = rsqrtf((float)c);
    }
  }
}

// Pass 5b: dst side — per-node counts -> row_ptr/ii/coi, then clustered csr_src fill.
__global__ __launch_bounds__(256) void k_bfill2(const int* __restrict__ ebuf,
                                                const int* __restrict__ bbase,
                                                const float* __restrict__ oi,
                                                int* __restrict__ row_ptr,
                                                int* __restrict__ csr_src,
                                                float* __restrict__ ii,
                                                float* __restrict__ coi) {
  __shared__ unsigned cnt[128];
  __shared__ int start[128];
  const int b = blockIdx.x, t = threadIdx.x;
  const int node0 = b << BSHIFT;
  const int base = bbase[b], end = bbase[b + 1];
  if (t < 128) cnt[t] = 0u;
  __syncthreads();
  for (int j = base + t; j < end; j += 256)
    atomicAdd(&cnt[(unsigned)ebuf[j] >> 17], 1u);
  __syncthreads();
  if (t == 0) {
    int r = 0;
    for (int i = 0; i < 128; ++i) { start[i] = r; r += (int)cnt[i]; }
  }
  __syncthreads();
  if (t < 128) {
    int n = node0 + t;
    if (n < N_NODES) {
      row_ptr[n] = base + start[t];
      unsigned c = cnt[t]; if (c < 1u) c = 1u;
      float iv = rsqrtf((float)c);
      ii[n] = iv;
      coi[n] = iv * oi[n];  // relu(ii*agg)*oi == (ii*oi)*relu(agg)
    }
  }
  __syncthreads();
  if (t < 128) cnt[t] = (unsigned)start[t];
  __syncthreads();
  for (int j = base + t; j < end; j += 256) {
    int pk = ebuf[j];
    unsigned dn = (unsigned)pk >> 17;
    unsigned slot = atomicAdd(&cnt[dn], 1u);
    csr_src[base + (int)slot] = pk & 0x1FFFF;
  }
}

// ---------------- GEMM1 (MFMA bf16): h1b = bf16((x*oi) @ W1), 100k x 128 x 128 ----------------

#define LPAD 136

__global__ __launch_bounds__(256) void k_gemm1(const float* __restrict__ x,
                                               const float* __restrict__ oi,
                                               const unsigned short* __restrict__ Wt1,
                                               unsigned short* __restrict__ h1b) {
  __shared__ unsigned short Xs[64 * LPAD];
  __shared__ unsigned short Ws[128 * LPAD];
  const int t = threadIdx.x;
  const int row0 = blockIdx.x * 64;
#pragma unroll
  for (int j = 0; j < 8; ++j) {
    int q = t + 256 * j;
    int n = q >> 4, c = q & 15;
    *(uint4*)(Ws + n * LPAD + c * 8) = *(const uint4*)(Wt1 + n * 128 + c * 8);
  }
#pragma unroll
  for (int j = 0; j < 4; ++j) {
    int q = t + 256 * j;
    int r = q >> 4, c = q & 15;
    int gr = row0 + r; if (gr >= N_NODES) gr = N_NODES - 1;
    const float* xp = x + (size_t)gr * 128 + c * 8;
    float4 v0 = *(const float4*)(xp);
    float4 v1 = *(const float4*)(xp + 4);
    float s = oi[gr];
    uint4 pk;
    pk.x = pack_bf16x2(v0.x * s, v0.y * s);
    pk.y = pack_bf16x2(v0.z * s, v0.w * s);
    pk.z = pack_bf16x2(v1.x * s, v1.y * s);
    pk.w = pack_bf16x2(v1.z * s, v1.w * s);
    *(uint4*)(Xs + r * LPAD + c * 8) = pk;
  }
  __syncthreads();
  const int w = t >> 6, lane = t & 63;
  const int m = lane & 15;
  const int q8 = (lane >> 4) * 8;
  f32x4 acc[8];
#pragma unroll
  for (int i = 0; i < 8; ++i) acc[i] = (f32x4){0.f, 0.f, 0.f, 0.f};
  const unsigned short* xrow = Xs + (w * 16 + m) * LPAD;
#pragma unroll
  for (int ks = 0; ks < 4; ++ks) {
    bf16x8 a = *(const bf16x8*)(xrow + ks * 32 + q8);
#pragma unroll
    for (int ct = 0; ct < 8; ++ct) {
      bf16x8 b = *(const bf16x8*)(Ws + (ct * 16 + m) * LPAD + ks * 32 + q8);
      acc[ct] = __builtin_amdgcn_mfma_f32_16x16x32_bf16(a, b, acc[ct], 0, 0, 0);
    }
  }
  const int rbase = row0 + w * 16 + (lane >> 4) * 4;
#pragma unroll
  for (int ct = 0; ct < 8; ++ct) {
    int coln = ct * 16 + m;
#pragma unroll
    for (int r = 0; r < 4; ++r) {
      int grow = rbase + r;
      if (grow < N_NODES) h1b[(size_t)grow * 128 + coln] = bf16u(acc[ct][r]);
    }
  }
}

// ---------------- AGG1: g = bf16(coi * relu(sum h1[src]))  (MLP x8 gather) ----------------

__global__ __launch_bounds__(256) void k_agg1(const unsigned short* __restrict__ h1b,
                                              const int* __restrict__ csr_src,
                                              const int* __restrict__ row_ptr,
                                              const float* __restrict__ coi,
                                              unsigned short* __restrict__ g) {
  const int t = threadIdx.x;
  const int node = blockIdx.x * 16 + (t >> 4);
  const int c = t & 15;
  const int beg = row_ptr[node];
  const int end = row_ptr[node + 1];
  float4 a0 = make_float4(0.f, 0.f, 0.f, 0.f);
  float4 a1 = make_float4(0.f, 0.f, 0.f, 0.f);
  int j = beg;
  for (; j + 8 <= end; j += 8) {
    uint4 v[8];
#pragma unroll
    for (int i = 0; i < 8; ++i) {
      int s = csr_src[j + i];
      v[i] = *(const uint4*)(h1b + (size_t)s * 128 + 8 * c);
    }
#pragma unroll
    for (int i = 0; i < 8; ++i) {
      a0.x += bf_lo(v[i].x); a0.y += bf_hi(v[i].x);
      a0.z += bf_lo(v[i].y); a0.w += bf_hi(v[i].y);
      a1.x += bf_lo(v[i].z); a1.y += bf_hi(v[i].z);
      a1.z += bf_lo(v[i].w); a1.w += bf_hi(v[i].w);
    }
  }
  for (; j < end; ++j) {
    int s = csr_src[j];
    uint4 v = *(const uint4*)(h1b + (size_t)s * 128 + 8 * c);
    a0.x += bf_lo(v.x); a0.y += bf_hi(v.x); a0.z += bf_lo(v.y); a0.w += bf_hi(v.y);
    a1.x += bf_lo(v.z); a1.y += bf_hi(v.z); a1.z += bf_lo(v.w); a1.w += bf_hi(v.w);
  }
  float sc = coi[node];
  uint4 pk;
  pk.x = pack_bf16x2(fmaxf(a0.x, 0.f) * sc, fmaxf(a0.y, 0.f) * sc);
  pk.y = pack_bf16x2(fmaxf(a0.z, 0.f) * sc, fmaxf(a0.w, 0.f) * sc);
  pk.z = pack_bf16x2(fmaxf(a1.x, 0.f) * sc, fmaxf(a1.y, 0.f) * sc);
  pk.w = pack_bf16x2(fmaxf(a1.z, 0.f) * sc, fmaxf(a1.w, 0.f) * sc);
  *(uint4*)(g + (size_t)node * 128 + 8 * c) = pk;
}

// ---------------- GEMM2 (MFMA bf16): h2b = bf16(g @ W2), 100k x 128 x 40 (N pad 48) ----------------

__global__ __launch_bounds__(256) void k_gemm2(const unsigned short* __restrict__ gb,
                                               const unsigned short* __restrict__ Wt2,
                                               unsigned short* __restrict__ h2b) {
  __shared__ unsigned short Gs[64 * LPAD];
  __shared__ unsigned short Ws[48 * LPAD];
  const int t = threadIdx.x;
  const int row0 = blockIdx.x * 64;
#pragma unroll
  for (int j = 0; j < 3; ++j) {
    int q = t + 256 * j;
    int n = q >> 4, c = q & 15;
    *(uint4*)(Ws + n * LPAD + c * 8) = *(const uint4*)(Wt2 + n * 128 + c * 8);
  }
#pragma unroll
  for (int j = 0; j < 4; ++j) {
    int q = t + 256 * j;
    int r = q >> 4, c = q & 15;
    int gr = row0 + r; if (gr >= N_NODES) gr = N_NODES - 1;
    *(uint4*)(Gs + r * LPAD + c * 8) = *(const uint4*)(gb + (size_t)gr * 128 + c * 8);
  }
  __syncthreads();
  const int w = t >> 6, lane = t & 63;
  const int m = lane & 15;
  const int q8 = (lane >> 4) * 8;
  f32x4 acc[3];
#pragma unroll
  for (int i = 0; i < 3; ++i) acc[i] = (f32x4){0.f, 0.f, 0.f, 0.f};
  const unsigned short* grow_p = Gs + (w * 16 + m) * LPAD;
#pragma unroll
  for (int ks = 0; ks < 4; ++ks) {
    bf16x8 a = *(const bf16x8*)(grow_p + ks * 32 + q8);
#pragma unroll
    for (int ct = 0; ct < 3; ++ct) {
      bf16x8 b = *(const bf16x8*)(Ws + (ct * 16 + m) * LPAD + ks * 32 + q8);
      acc[ct] = __builtin_amdgcn_mfma_f32_16x16x32_bf16(a, b, acc[ct], 0, 0, 0);
    }
  }
  const int rbase = row0 + w * 16 + (lane >> 4) * 4;
#pragma unroll
  for (int ct = 0; ct < 3; ++ct) {
    int coln = ct * 16 + m;
    if (coln < 40) {
#pragma unroll
      for (int r = 0; r < 4; ++r) {
        int grow = rbase + r;
        if (grow < N_NODES) h2b[(size_t)grow * 40 + coln] = bf16u(acc[ct][r]);
      }
    }
  }
}

// ---------------- AGG2: out = ii * sum h2[src]  (MLP x4 gather, 40 ch fp32 out) ----------------

__global__ __launch_bounds__(256) void k_agg2(const unsigned short* __restrict__ h2b,
                                              const int* __restrict__ csr_src,
                                              const int* __restrict__ row_ptr,
                                              const float* __restrict__ ii,
                                              float* __restrict__ out) {
  const int t = threadIdx.x;
  const int node = blockIdx.x * 16 + (t >> 4);
  const int c = t & 15;
  if (c >= 10) return;
  const int beg = row_ptr[node];
  const int end = row_ptr[node + 1];
  float4 acc = make_float4(0.f, 0.f, 0.f, 0.f);
  int j = beg;
  for (; j + 4 <= end; j += 4) {
    int s0 = csr_src[j], s1 = csr_src[j + 1], s2 = csr_src[j + 2], s3 = csr_src[j + 3];
    uint2 v0 = *(const uint2*)(h2b + (size_t)s0 * 40 + 4 * c);
    uint2 v1 = *(const uint2*)(h2b + (size_t)s1 * 40 + 4 * c);
    uint2 v2 = *(const uint2*)(h2b + (size_t)s2 * 40 + 4 * c);
    uint2 v3 = *(const uint2*)(h2b + (size_t)s3 * 40 + 4 * c);
    acc.x += bf_lo(v0.x); acc.y += bf_hi(v0.x); acc.z += bf_lo(v0.y); acc.w += bf_hi(v0.y);
    acc.x += bf_lo(v1.x); acc.y += bf_hi(v1.x); acc.z += bf_lo(v1.y); acc.w += bf_hi(v1.y);
    acc.x += bf_lo(v2.x); acc.y += bf_hi(v2.x); acc.z += bf_lo(v2.y); acc.w += bf_hi(v2.y);
    acc.x += bf_lo(v3.x); acc.y += bf_hi(v3.x); acc.z += bf_lo(v3.y); acc.w += bf_hi(v3.y);
  }
  for (; j < end; ++j) {
    int s = csr_src[j];
    uint2 v = *(const uint2*)(h2b + (size_t)s * 40 + 4 * c);
    acc.x += bf_lo(v.x); acc.y += bf_hi(v.x); acc.z += bf_lo(v.y); acc.w += bf_hi(v.y);
  }
  float sc = ii[node];
  acc.x *= sc; acc.y *= sc; acc.z *= sc; acc.w *= sc;
  *(float4*)(out + (size_t)node * 40 + 4 * c) = acc;
}

// ---------------- launch ----------------

extern "C" void kernel_launch(void* const* d_in, const int* in_sizes, int n_in,
                              void* d_out, int out_size, void* d_ws, size_t ws_size,
                              hipStream_t stream) {
  const float* x  = (const float*)d_in[0];
  const int* ei   = (const int*)d_in[1];
  const float* W1 = (const float*)d_in[2];
  const float* W2 = (const float*)d_in[3];
  const int* src = ei;
  const int* dst = ei + N_EDGES;
  float* out = (float*)d_out;

  char* p = (char*)d_ws;
  auto alloc = [&](size_t b) -> void* {
    char* r = p;
    p += (b + 255) & ~(size_t)255;
    return (void*)r;
  };
  float* oi            = (float*)alloc((size_t)N_NODES * 4);
  float* ii            = (float*)alloc((size_t)N_NODES * 4);
  float* coi           = (float*)alloc((size_t)N_NODES * 4);
  int* row_ptr         = (int*)alloc((size_t)(N_NODES + 1) * 4);
  unsigned* histGd     = (unsigned*)alloc((size_t)NBUCK * NCHUNK * 4);
  unsigned* histGs     = (unsigned*)alloc((size_t)NBUCK * NCHUNK * 4);
  unsigned* btot       = (unsigned*)alloc((size_t)2 * NBUCK * 4);
  int* bbase           = (int*)alloc((size_t)(NBUCK + 1) * 4);
  int* sbase           = (int*)alloc((size_t)(NBUCK + 1) * 4);
  int* ebuf            = (int*)alloc((size_t)N_EDGES * 4);
  unsigned char* ebuf2 = (unsigned char*)alloc((size_t)N_EDGES);
  int* csr_src         = (int*)alloc((size_t)N_EDGES * 4);
  unsigned short* Wt1  = (unsigned short*)alloc((size_t)128 * 128 * 2);
  unsigned short* Wt2  = (unsigned short*)alloc((size_t)48 * 128 * 2);
  unsigned short* h1b  = (unsigned short*)alloc((size_t)N_NODES * 128 * 2);
  unsigned short* g    = (unsigned short*)alloc((size_t)N_NODES * 128 * 2);
  unsigned short* h2b  = (unsigned short*)alloc((size_t)N_NODES * 40 * 2);

  k_prepw<<<64, 256, 0, stream>>>(W1, W2, Wt1, Wt2);
  k_hist<<<NCHUNK, 256, 0, stream>>>(src, dst, histGd, histGs);
  k_offs<<<2 * NBUCK, 256, 0, stream>>>(histGd, histGs, btot);
  k_bscan2<<<2, 1024, 0, stream>>>(btot, bbase, sbase, row_ptr);
  k_part<<<NCHUNK, 256, 0, stream>>>(src, dst, histGd, histGs, bbase, sbase, ebuf, ebuf2);
  k_count_src<<<NBUCK, 256, 0, stream>>>(ebuf2, sbase, oi);
  k_bfill2<<<NBUCK, 256, 0, stream>>>(ebuf, bbase, oi, row_ptr, csr_src, ii, coi);
  k_gemm1<<<(N_NODES + 63) / 64, 256, 0, stream>>>(x, oi, Wt1, h1b);
  k_agg1<<<N_NODES / 16, 256, 0, stream>>>(h1b, csr_src, row_ptr, coi, g);
  k_gemm2<<<(N_NODES + 63) / 64, 256, 0, stream>>>(g, Wt2, h2b);
  k_agg2<<<N_NODES / 16, 256, 0, stream>>>(h2b, csr_src, row_ptr, ii, out);
}